// Round 7
// baseline (2378.803 us; speedup 1.0000x reference)
//
#include <hip/hip_runtime.h>
#include <hip/hip_bf16.h>
#include <math.h>

#define NV 50000
#define NE 256
#define NH 256
#define NT 20
#define NB 64
#define NL 512
#define TAG_START 18
#define TAG_STOP 19
#define NEGV -10000.0f

typedef unsigned short ushortT;
typedef __attribute__((ext_vector_type(4))) float f32x4;
typedef __attribute__((ext_vector_type(8))) short short8;

#define PINV(x) asm volatile("" : "+v"(x))

__device__ __forceinline__ float sigf_slow(float x) { return 1.0f / (1.0f + expf(-x)); }
__device__ __forceinline__ float fsig(float x) { return 1.0f / (1.0f + __expf(-x)); }
__device__ __forceinline__ float ftanh(float x) { return 1.0f - 2.0f / (1.0f + __expf(2.0f * x)); }
__device__ __forceinline__ ushortT f2bf(float f) {
    unsigned int u = __float_as_uint(f);
    u += 0x7fffu + ((u >> 16) & 1u);
    return (ushortT)(u >> 16);
}
__device__ __forceinline__ float bf2f(unsigned int bits16) {
    return __uint_as_float(bits16 << 16);
}

// write one 16B weight fragment into 4 literal AGPRs
#define WRW(A0,A1,A2,A3,PTR) do {                                   \
    int4 _u = *(const int4*)(PTR);                                  \
    asm volatile("v_accvgpr_write_b32 a" #A0 ", %0\n\t"             \
                 "v_accvgpr_write_b32 a" #A1 ", %1\n\t"             \
                 "v_accvgpr_write_b32 a" #A2 ", %2\n\t"             \
                 "v_accvgpr_write_b32 a" #A3 ", %3"                 \
                 :: "v"(_u.x), "v"(_u.y), "v"(_u.z), "v"(_u.w)      \
                 : "a" #A0, "a" #A1, "a" #A2, "a" #A3);             \
} while (0)

// 4 MFMAs (one per gate) for one k-tile; B operands at literal AGPR ranges
#define ACLOB "a0","a1","a2","a3","a4","a5","a6","a7","a8","a9","a10","a11","a12","a13","a14","a15"
#define MFMA4(B0a,B0b,B1a,B1b,B2a,B2b,B3a,B3b,AF)                                        \
    asm volatile("v_mfma_f32_16x16x32_bf16 a[0:3], %0, a[" #B0a ":" #B0b "], a[0:3]\n\t" \
                 "v_mfma_f32_16x16x32_bf16 a[4:7], %0, a[" #B1a ":" #B1b "], a[4:7]\n\t" \
                 "v_mfma_f32_16x16x32_bf16 a[8:11], %0, a[" #B2a ":" #B2b "], a[8:11]\n\t" \
                 "v_mfma_f32_16x16x32_bf16 a[12:15], %0, a[" #B3a ":" #B3b "], a[12:15]" \
                 :: "v"(AF) : ACLOB)

// ===========================================================================
// FAST PATH
// ===========================================================================

__global__ __launch_bounds__(256) void k_cvtw(
    const float* __restrict__ whh_f, const float* __restrict__ whh_b,
    const float* __restrict__ wih_f, const float* __restrict__ wih_b,
    ushortT* __restrict__ whh16, ushortT* __restrict__ wih16)
{
    int idx = blockIdx.x * 256 + threadIdx.x;     // < 262144
    const float* s; ushortT* d;
    switch (blockIdx.y) {
        case 0: s = whh_f; d = whh16;            break;
        case 1: s = whh_b; d = whh16 + 262144;   break;
        case 2: s = wih_f; d = wih16;            break;
        default: s = wih_b; d = wih16 + 262144;  break;
    }
    d[idx] = f2bf(s[idx]);
}

__global__ __launch_bounds__(1024) void k_bias(
    const float* __restrict__ bih_f, const float* __restrict__ bhh_f,
    const float* __restrict__ bih_b, const float* __restrict__ bhh_b,
    float* __restrict__ biasc)
{
    int n = threadIdx.x;
    if (blockIdx.x == 0) biasc[n] = bih_f[n] + bhh_f[n];
    else                 biasc[1024 + n] = bih_b[n] + bhh_b[n];
}

// K-gin: gin[dirg][t][col*16 + row] = x_t @ Wih^T + bias  (bf16 MFMA)
__global__
__attribute__((amdgpu_flat_work_group_size(512, 512)))
__attribute__((amdgpu_waves_per_eu(2, 2)))
void k_gin_mfma(
    const int* __restrict__ sent, const int* __restrict__ lens,
    const float* __restrict__ emb, const ushortT* __restrict__ wih16,
    const float* __restrict__ biasc, float* __restrict__ gin,
    int chunk_start, int CH)
{
    const int g = blockIdx.x, tsub = blockIdx.y;
    const int dir = blockIdx.z >> 1, half = blockIdx.z & 1;
    const int gmax = lens[g * 16];
    const int tt0 = tsub * 16;
    if (chunk_start + tt0 >= gmax) return;

    const int tid = threadIdx.x;
    const int w = tid >> 6, l = tid & 63, lr = l & 15, lg = l >> 4;

    __shared__ char x_raw[16 * 512];

    const int ucol = half * 128 + w * 16 + lr;
    short8 bfr[4][8];
    float bias_l[4];
    const ushortT* wsrc = wih16 + dir * 262144;
#pragma unroll
    for (int nt = 0; nt < 4; ++nt) {
        int col = nt * 256 + ucol;
        bias_l[nt] = biasc[dir * 1024 + col];
#pragma unroll
        for (int kt = 0; kt < 8; ++kt)
            bfr[nt][kt] = *(const short8*)(wsrc + (size_t)col * 256 + kt * 32 + lg * 8);
    }
#pragma unroll
    for (int nt = 0; nt < 4; ++nt) {
        PINV(bias_l[nt]);
#pragma unroll
        for (int kt = 0; kt < 8; ++kt) PINV(bfr[nt][kt]);
    }

    const int srow = tid >> 5, sseg = tid & 31;
    const int slen = lens[g * 16 + srow];
    const int sb = (g * 16 + srow) * 512;

    for (int i = 0; i < 16; ++i) {
        int tg = chunk_start + tt0 + i;
        if (tg >= gmax) break;

        int tsrc = dir ? (slen - 1 - tg) : tg;
        if (tsrc < 0) tsrc = 0;
        if (tsrc > 511) tsrc = 511;
        int tok = sent[sb + tsrc];
        const float* es = emb + (size_t)tok * 256 + sseg * 8;
        float4 e0 = *(const float4*)es;
        float4 e1 = *(const float4*)(es + 4);
        short8 xv;
        xv[0] = (short)f2bf(e0.x); xv[1] = (short)f2bf(e0.y);
        xv[2] = (short)f2bf(e0.z); xv[3] = (short)f2bf(e0.w);
        xv[4] = (short)f2bf(e1.x); xv[5] = (short)f2bf(e1.y);
        xv[6] = (short)f2bf(e1.z); xv[7] = (short)f2bf(e1.w);
        int sa = (srow * 512 + sseg * 16) ^ ((srow & 7) << 4);
        *(short8*)&x_raw[sa] = xv;
        __syncthreads();

        short8 af[8];
#pragma unroll
        for (int kt = 0; kt < 8; ++kt) {
            int a = (lr * 512 + kt * 64 + lg * 16) ^ ((lr & 7) << 4);
            af[kt] = *(const short8*)&x_raw[a];
        }
        f32x4 acc[4];
#pragma unroll
        for (int nt = 0; nt < 4; ++nt) {
            acc[nt][0] = bias_l[nt]; acc[nt][1] = bias_l[nt];
            acc[nt][2] = bias_l[nt]; acc[nt][3] = bias_l[nt];
        }
#pragma unroll
        for (int kt = 0; kt < 8; ++kt)
#pragma unroll
            for (int nt = 0; nt < 4; ++nt)
                acc[nt] = __builtin_amdgcn_mfma_f32_16x16x32_bf16(af[kt], bfr[nt][kt], acc[nt], 0, 0, 0);

        float* ginp = gin + ((size_t)((dir * 4 + g) * CH + (tt0 + i))) * 16384;
#pragma unroll
        for (int nt = 0; nt < 4; ++nt)
            *(f32x4*)(ginp + (nt * 256 + ucol) * 16 + lg * 4) = acc[nt];
        __syncthreads();
    }
}

// K-rec: weights in HARD-CODED AGPRs a16-a143 (compiler cannot spill them);
//   acc a0-a15 initialized from gin each step. 2 CUs per (group,dir) with
//   LLC mailbox h-exchange.
__global__
__attribute__((amdgpu_flat_work_group_size(512, 512)))
__attribute__((amdgpu_waves_per_eu(2, 2)))
void k_rec_mfma(
    const int* __restrict__ lens, const ushortT* __restrict__ whh16,
    const float* __restrict__ gin, ushortT* __restrict__ hout,
    ushortT* __restrict__ st_h, float* __restrict__ st_c,
    ushortT* __restrict__ hex, unsigned int* __restrict__ flags,
    int chunk_start, int CH)
{
    const int g = blockIdx.x, dir = blockIdx.y, half = blockIdx.z;
    const int gmax = lens[g * 16];
    const int nsteps = min(CH, gmax - chunk_start);
    if (nsteps <= 0) return;

    const int tid = threadIdx.x;
    const int w = tid >> 6, l = tid & 63, lr = l & 15, lg = l >> 4;

    __shared__ char h_s[2][8192];   // [buf][row*512B + unit*2B], XOR-swizzled

    int lenr[4];
#pragma unroll
    for (int r = 0; r < 4; ++r) lenr[r] = lens[g * 16 + lg * 4 + r];

    // ---- load weights into literal AGPRs a16..a143 -------------------------
    const int ucol = half * 128 + w * 16 + lr;
    {
        const ushortT* wsrc = whh16 + dir * 262144;
        const ushortT* p0 = wsrc + (size_t)(0 * 256 + ucol) * 256 + lg * 8;
        const ushortT* p1 = wsrc + (size_t)(1 * 256 + ucol) * 256 + lg * 8;
        const ushortT* p2 = wsrc + (size_t)(2 * 256 + ucol) * 256 + lg * 8;
        const ushortT* p3 = wsrc + (size_t)(3 * 256 + ucol) * 256 + lg * 8;
        WRW( 16, 17, 18, 19, p0 +   0); WRW( 20, 21, 22, 23, p0 +  32);
        WRW( 24, 25, 26, 27, p0 +  64); WRW( 28, 29, 30, 31, p0 +  96);
        WRW( 32, 33, 34, 35, p0 + 128); WRW( 36, 37, 38, 39, p0 + 160);
        WRW( 40, 41, 42, 43, p0 + 192); WRW( 44, 45, 46, 47, p0 + 224);
        WRW( 48, 49, 50, 51, p1 +   0); WRW( 52, 53, 54, 55, p1 +  32);
        WRW( 56, 57, 58, 59, p1 +  64); WRW( 60, 61, 62, 63, p1 +  96);
        WRW( 64, 65, 66, 67, p1 + 128); WRW( 68, 69, 70, 71, p1 + 160);
        WRW( 72, 73, 74, 75, p1 + 192); WRW( 76, 77, 78, 79, p1 + 224);
        WRW( 80, 81, 82, 83, p2 +   0); WRW( 84, 85, 86, 87, p2 +  32);
        WRW( 88, 89, 90, 91, p2 +  64); WRW( 92, 93, 94, 95, p2 +  96);
        WRW( 96, 97, 98, 99, p2 + 128); WRW(100,101,102,103, p2 + 160);
        WRW(104,105,106,107, p2 + 192); WRW(108,109,110,111, p2 + 224);
        WRW(112,113,114,115, p3 +   0); WRW(116,117,118,119, p3 +  32);
        WRW(120,121,122,123, p3 +  64); WRW(124,125,126,127, p3 +  96);
        WRW(128,129,130,131, p3 + 128); WRW(132,133,134,135, p3 + 160);
        WRW(136,137,138,139, p3 + 192); WRW(140,141,142,143, p3 + 224);
    }

    // state init / restore
    float c[4];
    if (chunk_start == 0) {
#pragma unroll
        for (int r = 0; r < 4; ++r) c[r] = 0.0f;
        for (int i = tid; i < 2048; i += 512) ((int*)h_s[0])[i] = 0;
    } else {
        const float* cs = st_c + ((size_t)((dir * 4 + g) * 2 + half)) * 2048 + tid * 4;
#pragma unroll
        for (int r = 0; r < 4; ++r) c[r] = cs[r];
        const int* hs = (const int*)st_h + (dir * 4 + g) * 2048;
        for (int i = tid; i < 2048; i += 512) ((int*)h_s[0])[i] = hs[i];
    }
    __syncthreads();

    // exchange constants
    unsigned int* exu = (unsigned int*)(hex + (dir * 4 + g) * 8192);  // 2 slots x 2048 uints
    unsigned int* flagMe = flags + (dir * 4 + g) * 2 + half;
    unsigned int* flagPeer = flags + (dir * 4 + g) * 2 + (half ^ 1);

    int own_lds[2], own_gid[2], peer_lds[2], peer_gid[2];
#pragma unroll
    for (int s2 = 0; s2 < 2; ++s2) {
        int i = tid * 2 + s2;
        int row = i >> 6, j = i & 63;
        int mu = half * 128 + j * 2;
        own_lds[s2] = (row * 512 + mu * 2) ^ ((row & 7) << 4);
        own_gid[s2] = row * 128 + half * 64 + j;
        int pu = (half ^ 1) * 128 + j * 2;
        peer_lds[s2] = (row * 512 + pu * 2) ^ ((row & 7) << 4);
        peer_gid[s2] = row * 128 + (half ^ 1) * 64 + j;
    }

    const float* ginp = gin + ((size_t)((dir * 4 + g) * CH)) * 16384;
    int p = 0;
    for (int tt = 0; tt < nsteps; ++tt) {
        const int t_glob = chunk_start + tt;

        // gin (input projection) for my 4 gate-cols -> acc init
        f32x4 gv[4];
#pragma unroll
        for (int nt = 0; nt < 4; ++nt)
            gv[nt] = *(const f32x4*)(ginp + (size_t)tt * 16384 + (nt * 256 + ucol) * 16 + lg * 4);

        asm volatile(
            "v_accvgpr_write_b32 a0, %0\n\t"  "v_accvgpr_write_b32 a1, %1\n\t"
            "v_accvgpr_write_b32 a2, %2\n\t"  "v_accvgpr_write_b32 a3, %3\n\t"
            "v_accvgpr_write_b32 a4, %4\n\t"  "v_accvgpr_write_b32 a5, %5\n\t"
            "v_accvgpr_write_b32 a6, %6\n\t"  "v_accvgpr_write_b32 a7, %7\n\t"
            "v_accvgpr_write_b32 a8, %8\n\t"  "v_accvgpr_write_b32 a9, %9\n\t"
            "v_accvgpr_write_b32 a10, %10\n\t" "v_accvgpr_write_b32 a11, %11\n\t"
            "v_accvgpr_write_b32 a12, %12\n\t" "v_accvgpr_write_b32 a13, %13\n\t"
            "v_accvgpr_write_b32 a14, %14\n\t" "v_accvgpr_write_b32 a15, %15\n\t"
            "s_nop 1"
            :: "v"(gv[0][0]), "v"(gv[0][1]), "v"(gv[0][2]), "v"(gv[0][3]),
               "v"(gv[1][0]), "v"(gv[1][1]), "v"(gv[1][2]), "v"(gv[1][3]),
               "v"(gv[2][0]), "v"(gv[2][1]), "v"(gv[2][2]), "v"(gv[2][3]),
               "v"(gv[3][0]), "v"(gv[3][1]), "v"(gv[3][2]), "v"(gv[3][3])
            : ACLOB);

        // h @ Whh^T: 8 k-tiles x 4 gates, weights resident in AGPR
        const char* hb = h_s[p];
#define STEP_KT(KT, B0a,B0b,B1a,B1b,B2a,B2b,B3a,B3b) {                      \
            int a_ = (lr * 512 + (KT) * 64 + lg * 16) ^ ((lr & 7) << 4);    \
            short8 af = *(const short8*)&hb[a_];                            \
            MFMA4(B0a,B0b,B1a,B1b,B2a,B2b,B3a,B3b, af); }
        STEP_KT(0,  16,19,  48,51,  80,83, 112,115)
        STEP_KT(1,  20,23,  52,55,  84,87, 116,119)
        STEP_KT(2,  24,27,  56,59,  88,91, 120,123)
        STEP_KT(3,  28,31,  60,63,  92,95, 124,127)
        STEP_KT(4,  32,35,  64,67,  96,99, 128,131)
        STEP_KT(5,  36,39,  68,71, 100,103, 132,135)
        STEP_KT(6,  40,43,  72,75, 104,107, 136,139)
        STEP_KT(7,  44,47,  76,79, 108,111, 140,143)
#undef STEP_KT

        // read accumulators back (with MFMA->VALU hazard nops)
        float o0,o1,o2,o3,o4,o5,o6,o7,o8,o9,o10,o11,o12,o13,o14,o15;
        asm volatile(
            "s_nop 7\n\ts_nop 7\n\t"
            "v_accvgpr_read_b32 %0, a0\n\t"   "v_accvgpr_read_b32 %1, a1\n\t"
            "v_accvgpr_read_b32 %2, a2\n\t"   "v_accvgpr_read_b32 %3, a3\n\t"
            "v_accvgpr_read_b32 %4, a4\n\t"   "v_accvgpr_read_b32 %5, a5\n\t"
            "v_accvgpr_read_b32 %6, a6\n\t"   "v_accvgpr_read_b32 %7, a7\n\t"
            "v_accvgpr_read_b32 %8, a8\n\t"   "v_accvgpr_read_b32 %9, a9\n\t"
            "v_accvgpr_read_b32 %10, a10\n\t" "v_accvgpr_read_b32 %11, a11\n\t"
            "v_accvgpr_read_b32 %12, a12\n\t" "v_accvgpr_read_b32 %13, a13\n\t"
            "v_accvgpr_read_b32 %14, a14\n\t" "v_accvgpr_read_b32 %15, a15"
            : "=v"(o0),"=v"(o1),"=v"(o2),"=v"(o3),"=v"(o4),"=v"(o5),"=v"(o6),"=v"(o7),
              "=v"(o8),"=v"(o9),"=v"(o10),"=v"(o11),"=v"(o12),"=v"(o13),"=v"(o14),"=v"(o15));

        float gi[4] = {o0, o1, o2, o3};      // gate i, rows r=0..3
        float gf[4] = {o4, o5, o6, o7};      // gate f
        float gg[4] = {o8, o9, o10, o11};    // gate g
        float go[4] = {o12, o13, o14, o15};  // gate o

        // pointwise cell (lane has all 4 gates of unit ucol, rows lg*4+r)
        char* hw = h_s[p ^ 1];
#pragma unroll
        for (int r = 0; r < 4; ++r) {
            float cn = fsig(gf[r]) * c[r] + fsig(gi[r]) * ftanh(gg[r]);
            float hn = fsig(go[r]) * ftanh(cn);
            c[r] = cn;
            ushortT hb16 = f2bf(hn);
            int row = lg * 4 + r;
            int a_ = (row * 512 + ucol * 2) ^ ((row & 7) << 4);
            *(ushortT*)&hw[a_] = hb16;
            if (t_glob < lenr[r]) {
                int tp = dir ? (lenr[r] - 1 - t_glob) : t_glob;
                hout[((size_t)((g * 16 + row) * 512 + tp)) * 512 + dir * 256 + ucol] = hb16;
            }
        }
        __syncthreads();   // own half of h(t+1) complete in LDS

        // publish own half to LLC mailbox
        unsigned int* exs = exu + ((t_glob + 1) & 1) * 2048;
#pragma unroll
        for (int s2 = 0; s2 < 2; ++s2) {
            unsigned int v = *(const unsigned int*)&hw[own_lds[s2]];
            __hip_atomic_store(&exs[own_gid[s2]], v, __ATOMIC_RELAXED, __HIP_MEMORY_SCOPE_AGENT);
        }
        __syncthreads();   // drains vmcnt -> all stores acked at LLC

        if (tid == 0) {
            __hip_atomic_store(flagMe, (unsigned int)(t_glob + 1), __ATOMIC_RELEASE, __HIP_MEMORY_SCOPE_AGENT);
            int guard = 0;
            while (__hip_atomic_load(flagPeer, __ATOMIC_RELAXED, __HIP_MEMORY_SCOPE_AGENT) < (unsigned int)(t_glob + 1)
                   && ++guard < (1 << 16)) {}
        }
        __syncthreads();

        // fetch peer half into LDS
#pragma unroll
        for (int s2 = 0; s2 < 2; ++s2) {
            unsigned int v = __hip_atomic_load(&exs[peer_gid[s2]], __ATOMIC_RELAXED, __HIP_MEMORY_SCOPE_AGENT);
            *(unsigned int*)&hw[peer_lds[s2]] = v;
        }
        __syncthreads();
        p ^= 1;
    }

    // save state
    float* cs = st_c + ((size_t)((dir * 4 + g) * 2 + half)) * 2048 + tid * 4;
#pragma unroll
    for (int r = 0; r < 4; ++r) cs[r] = c[r];
    if (half == 0) {
        int* hs = (int*)st_h + (dir * 4 + g) * 2048;
        for (int i = tid; i < 2048; i += 512) hs[i] = ((int*)h_s[p])[i];
    }
}

// K-scores: scores[b,t,:] = h[b,t,:] (bf16) @ w_out^T + b_out  (t < len)
__global__ __launch_bounds__(256) void k_scores_bf(
    const int* __restrict__ lens, const ushortT* __restrict__ hout,
    const float* __restrict__ w_out, const float* __restrict__ b_out,
    float* __restrict__ scores)
{
    const int b = blockIdx.y;
    const int t0 = blockIdx.x * 32;
    const int len = lens[b];
    if (t0 >= len) return;

    __shared__ float w_s[20 * 513];
    __shared__ float row_s[512];
    __shared__ float part_s[20][9];
    __shared__ float bo_s[20];

    const int tid = threadIdx.x;
    for (int e = tid; e < 20 * 512; e += 256) w_s[(e >> 9) * 513 + (e & 511)] = w_out[e];
    if (tid < 20) bo_s[tid] = b_out[tid];
    __syncthreads();

    const int tend = min(t0 + 32, len);
    const int tag = tid >> 3, sl = tid & 7;
    for (int t = t0; t < tend; ++t) {
        const ushortT* hr = hout + ((size_t)(b * 512 + t)) * 512;
        unsigned int v = ((const unsigned int*)hr)[tid];
        row_s[tid * 2] = bf2f(v & 0xffffu);
        row_s[tid * 2 + 1] = bf2f(v >> 16);
        __syncthreads();
        if (tid < 160) {
            float s = 0.0f;
#pragma unroll 8
            for (int j = 0; j < 64; ++j) {
                int k = sl + (((j + tag) & 63) << 3);
                s = fmaf(w_s[tag * 513 + k], row_s[k], s);
            }
            part_s[tag][sl] = s;
        }
        __syncthreads();
        if (tid < 20) {
            float s = bo_s[tid];
#pragma unroll
            for (int j = 0; j < 8; ++j) s += part_s[tid][j];
            scores[((size_t)(b * 512 + t)) * 20 + tid] = s;
        }
        __syncthreads();
    }
}

__global__ __launch_bounds__(64) void k_viterbi_s(
    const int* __restrict__ lens, const float* __restrict__ scores,
    const float* __restrict__ trans, float* __restrict__ out)
{
    const int b = blockIdx.x;
    const int lane = threadIdx.x;
    const int len = lens[b];

    __shared__ float tr_s[20][21];
    __shared__ float fv_s[20];
    __shared__ float term_s[20];
    __shared__ unsigned char bp_s[512][20];
    __shared__ unsigned char path_s[512];

    for (int e = lane; e < 400; e += 64) tr_s[e / 20][e % 20] = trans[e];
    if (lane < 20) fv_s[lane] = (lane == TAG_START) ? 0.0f : NEGV;
    __syncthreads();

    const float* sc = scores + ((size_t)(b << 9)) * 20;
    for (int t = 0; t < len; ++t) {
        float m = 0.0f; int arg = 0;
        if (lane < 20) {
            m = fv_s[0] + tr_s[lane][0]; arg = 0;
#pragma unroll
            for (int k = 1; k < 20; ++k) {
                float v = fv_s[k] + tr_s[lane][k];
                if (v > m) { m = v; arg = k; }
            }
            m += sc[t * 20 + lane];
        }
        __syncthreads();
        if (lane < 20) { fv_s[lane] = m; bp_s[t][lane] = (unsigned char)arg; }
        __syncthreads();
    }

    if (lane < 20) term_s[lane] = fv_s[lane] + tr_s[TAG_STOP][lane];
    __syncthreads();

    if (lane == 0) {
        float m = term_s[0]; int arg = 0;
        for (int k = 1; k < 20; ++k) if (term_s[k] > m) { m = term_s[k]; arg = k; }
        out[b] = m;
        int cur = arg;
        path_s[len - 1] = (unsigned char)cur;
        for (int j = len - 1; j >= 1; --j) {
            cur = bp_s[j][cur];
            path_s[j - 1] = (unsigned char)cur;
        }
    }
    __syncthreads();

    float* po = out + NB + ((size_t)b << 9);
    for (int p = lane; p < NL; p += 64) po[p] = (p < len) ? (float)path_s[p] : 0.0f;
}

// ===========================================================================
// FALLBACK PATH (round-2 proven)
// ===========================================================================
__global__ __launch_bounds__(256) void k_transpose_fb(
    const float* __restrict__ whh_f, const float* __restrict__ whh_b,
    const float* __restrict__ wih_f, const float* __restrict__ wih_b,
    float* __restrict__ thh_f, float* __restrict__ thh_b,
    float* __restrict__ tih_f, float* __restrict__ tih_b)
{
    int e = blockIdx.x * 256 + threadIdx.x;
    const float* wm; float* wt;
    switch (blockIdx.y) {
        case 0: wm = whh_f; wt = thh_f; break;
        case 1: wm = whh_b; wt = thh_b; break;
        case 2: wm = wih_f; wt = tih_f; break;
        default: wm = wih_b; wt = tih_b; break;
    }
    int n = e >> 8, k = e & 255;
    wt[k * 1024 + n] = wm[e];
}

__global__ __launch_bounds__(1024) void k_rec_fb(
    const int* __restrict__ sent, const int* __restrict__ lens,
    const float* __restrict__ emb,
    const float* __restrict__ thh_f, const float* __restrict__ thh_b,
    const float* __restrict__ tih_f, const float* __restrict__ tih_b,
    const float* __restrict__ b_ih_f, const float* __restrict__ b_hh_f,
    const float* __restrict__ b_ih_b, const float* __restrict__ b_hh_b,
    const float* __restrict__ w_out,
    float* __restrict__ sc_f, float* __restrict__ sc_b)
{
    const int b = blockIdx.x, dir = blockIdx.y;
    const int len = lens[b];
    const int n = threadIdx.x;
    const float* Whh = dir ? thh_b : thh_f;
    const float* Wih = dir ? tih_b : tih_f;
    const float* bi = dir ? b_ih_b : b_ih_f;
    const float* bh = dir ? b_hh_b : b_hh_f;
    float* scout = dir ? sc_b : sc_f;

    __shared__ float x_s[256];
    __shared__ float h_s[256];
    __shared__ float g_s[1024];
    __shared__ float bias_s[1024];
    __shared__ float wout_s[20 * 257];
    __shared__ float part_s[20][8];

    bias_s[n] = bi[n] + bh[n];
    for (int e = n; e < 20 * 256; e += 1024)
        wout_s[(e >> 8) * 257 + (e & 255)] = w_out[(e >> 8) * 512 + dir * 256 + (e & 255)];
    if (n < 256) h_s[n] = 0.0f;
    float c = 0.0f;
    __syncthreads();

    const int sbase = b << 9;
    for (int t = 0; t < len; ++t) {
        if (n < 256) {
            int ti = dir ? (len - 1 - t) : t;
            int tok = sent[sbase + ti];
            x_s[n] = emb[(size_t)tok * NE + n];
        }
        __syncthreads();
        float acc = bias_s[n];
        const float* wi = Wih + n;
        const float* wh = Whh + n;
#pragma unroll 8
        for (int k = 0; k < 256; ++k) {
            acc = fmaf(wh[(size_t)(k << 10)], h_s[k], acc);
            acc = fmaf(wi[(size_t)(k << 10)], x_s[k], acc);
        }
        g_s[n] = acc;
        __syncthreads();
        if (n < 256) {
            float ig = g_s[n], fg = g_s[n + 256], gg = g_s[n + 512], og = g_s[n + 768];
            float cn = sigf_slow(fg) * c + sigf_slow(ig) * tanhf(gg);
            float hn = sigf_slow(og) * tanhf(cn);
            c = cn; h_s[n] = hn;
        }
        __syncthreads();
        if (n < 160) {
            const int tag = n >> 3, sl = n & 7;
            const float* wrow = wout_s + tag * 257;
            float s = 0.0f;
#pragma unroll 8
            for (int j = 0; j < 32; ++j) { int k = sl + (j << 3); s = fmaf(wrow[k], h_s[k], s); }
            part_s[tag][sl] = s;
        }
        __syncthreads();
        if (n < 20) {
            float s = part_s[n][0];
#pragma unroll
            for (int j = 1; j < 8; ++j) s += part_s[n][j];
            int tp = dir ? (len - 1 - t) : t;
            scout[(size_t)(sbase + tp) * 20 + n] = s;
        }
    }
}

__global__ __launch_bounds__(64) void k_viterbi_fb(
    const int* __restrict__ lens,
    const float* __restrict__ sc_f, const float* __restrict__ sc_b,
    const float* __restrict__ b_out, const float* __restrict__ trans,
    float* __restrict__ out)
{
    const int b = blockIdx.x;
    const int lane = threadIdx.x;
    const int len = lens[b];

    __shared__ float tr_s[20][21];
    __shared__ float fv_s[20];
    __shared__ float term_s[20];
    __shared__ float bo_s[20];
    __shared__ unsigned char bp_s[512][20];
    __shared__ unsigned char path_s[512];

    for (int e = lane; e < 400; e += 64) tr_s[e / 20][e % 20] = trans[e];
    if (lane < 20) { fv_s[lane] = (lane == TAG_START) ? 0.0f : NEGV; bo_s[lane] = b_out[lane]; }
    __syncthreads();

    const size_t sb = (size_t)(b << 9) * 20;
    for (int t = 0; t < len; ++t) {
        float m = 0.0f; int arg = 0;
        if (lane < 20) {
            m = fv_s[0] + tr_s[lane][0]; arg = 0;
#pragma unroll
            for (int k = 1; k < 20; ++k) {
                float v = fv_s[k] + tr_s[lane][k];
                if (v > m) { m = v; arg = k; }
            }
            m += sc_f[sb + t * 20 + lane] + sc_b[sb + t * 20 + lane] + bo_s[lane];
        }
        __syncthreads();
        if (lane < 20) { fv_s[lane] = m; bp_s[t][lane] = (unsigned char)arg; }
        __syncthreads();
    }
    if (lane < 20) term_s[lane] = fv_s[lane] + tr_s[TAG_STOP][lane];
    __syncthreads();
    if (lane == 0) {
        float m = term_s[0]; int arg = 0;
        for (int k = 1; k < 20; ++k) if (term_s[k] > m) { m = term_s[k]; arg = k; }
        out[b] = m;
        int cur = arg;
        path_s[len - 1] = (unsigned char)cur;
        for (int j = len - 1; j >= 1; --j) { cur = bp_s[j][cur]; path_s[j - 1] = (unsigned char)cur; }
    }
    __syncthreads();
    float* po = out + NB + ((size_t)b << 9);
    for (int p = lane; p < NL; p += 64) po[p] = (p < len) ? (float)path_s[p] : 0.0f;
}

// ===========================================================================
extern "C" void kernel_launch(void* const* d_in, const int* in_sizes, int n_in,
                              void* d_out, int out_size, void* d_ws, size_t ws_size,
                              hipStream_t stream)
{
    const int*   sent   = (const int*)d_in[0];
    const int*   lens   = (const int*)d_in[1];
    const float* emb    = (const float*)d_in[2];
    const float* w_ih_f = (const float*)d_in[3];
    const float* w_hh_f = (const float*)d_in[4];
    const float* b_ih_f = (const float*)d_in[5];
    const float* b_hh_f = (const float*)d_in[6];
    const float* w_ih_b = (const float*)d_in[7];
    const float* w_hh_b = (const float*)d_in[8];
    const float* b_ih_b = (const float*)d_in[9];
    const float* b_hh_b = (const float*)d_in[10];
    const float* w_out  = (const float*)d_in[11];
    const float* b_out  = (const float*)d_in[12];
    const float* trans  = (const float*)d_in[13];
    float* out = (float*)d_out;

    char* w = (char*)d_ws;
    const size_t base = 38612992;
    int CH = 0;
    const int chs[6] = {512, 256, 192, 128, 64, 32};
    for (int i = 0; i < 6; ++i)
        if (base + (size_t)chs[i] * 524288 <= ws_size) { CH = chs[i]; break; }

    if (CH) {
        ushortT* whh16 = (ushortT*)(w);
        ushortT* wih16 = (ushortT*)(w + 1048576);
        float*   biasc = (float*)(w + 2097152);
        ushortT* st_h  = (ushortT*)(w + 2105344);
        float*   st_c  = (float*)(w + 2170880);
        ushortT* hex   = (ushortT*)(w + 2301952);
        unsigned int* flags = (unsigned int*)(w + 2433024);
        float*   scores= (float*)(w + 2437120);
        ushortT* hout  = (ushortT*)(w + 5058560);
        float*   gin   = (float*)(w + base);

        hipMemsetAsync(flags, 0, 4096, stream);
        k_cvtw<<<dim3(1024, 4), 256, 0, stream>>>(w_hh_f, w_hh_b, w_ih_f, w_ih_b, whh16, wih16);
        k_bias<<<2, 1024, 0, stream>>>(b_ih_f, b_hh_f, b_ih_b, b_hh_b, biasc);

        for (int cs = 0; cs < NL; cs += CH) {
            k_gin_mfma<<<dim3(4, CH / 16, 4), 512, 0, stream>>>(
                sent, lens, emb, wih16, biasc, gin, cs, CH);
            k_rec_mfma<<<dim3(4, 2, 2), 512, 0, stream>>>(
                lens, whh16, gin, hout, st_h, st_c, hex, flags, cs, CH);
        }
        k_scores_bf<<<dim3(16, 64), 256, 0, stream>>>(lens, hout, w_out, b_out, scores);
        k_viterbi_s<<<64, 64, 0, stream>>>(lens, scores, trans, out);
    } else {
        float* ws2   = (float*)d_ws;
        float* thh_f = ws2;
        float* thh_b = thh_f + 262144;
        float* tih_f = thh_b + 262144;
        float* tih_b = tih_f + 262144;
        float* sc_f  = tih_b + 262144;
        float* sc_b  = sc_f + (size_t)NB * NL * NT;

        k_transpose_fb<<<dim3(1024, 4), 256, 0, stream>>>(
            w_hh_f, w_hh_b, w_ih_f, w_ih_b, thh_f, thh_b, tih_f, tih_b);
        k_rec_fb<<<dim3(NB, 2), 1024, 0, stream>>>(
            sent, lens, emb, thh_f, thh_b, tih_f, tih_b,
            b_ih_f, b_hh_f, b_ih_b, b_hh_b, w_out, sc_f, sc_b);
        k_viterbi_fb<<<NB, 64, 0, stream>>>(lens, sc_f, sc_b, b_out, trans, out);
    }
}